// Round 7
// baseline (165.148 us; speedup 1.0000x reference)
//
#include <hip/hip_runtime.h>
#include <hip/hip_bf16.h>

// Problem constants
#define BS 16
#define LX 1024
#define LY 1024
#define H 512
#define MD 512
#define RY (BS * LY)   // 16384 rows of y

typedef __attribute__((ext_vector_type(8))) __bf16 bf16x8;
typedef __attribute__((ext_vector_type(4))) float floatx4;

// Async global->LDS, 16B per lane. HW dest = wave-uniform base + lane*16
// (guide §5 caveat m104/m108) — LDS layout must be contiguous in lane order.
__device__ __forceinline__ void load_lds16(const __bf16* g, __bf16* l) {
    __builtin_amdgcn_global_load_lds(
        (const __attribute__((address_space(1))) void*)g,
        (__attribute__((address_space(3))) void*)l,
        16, 0, 0);
}

// ---------------- prep_w2: f32 -> bf16 for W2 only (1 MB read) ----------------
__global__ __launch_bounds__(256) void prep_w2(const float* __restrict__ W2,
                                               __bf16* __restrict__ wb) {
    const int i = blockIdx.x * 256 + threadIdx.x;   // 0..32767, x8 floats
    const float4 a = *(const float4*)(W2 + (size_t)i * 8);
    const float4 b = *(const float4*)(W2 + (size_t)i * 8 + 4);
    bf16x8 v = { (__bf16)a.x, (__bf16)a.y, (__bf16)a.z, (__bf16)a.w,
                 (__bf16)b.x, (__bf16)b.y, (__bf16)b.z, (__bf16)b.w };
    *(bf16x8*)(wb + (size_t)i * 8) = v;
}

// ---------------- gemm: part[slice, m] = sum_n wo[n]*relu(Y@W2^T + b2) ----------------
// R7: pipelined direct-A + XOR-swizzled double-buffered Bs.
// Tile 64(M) x 128(N), BK=64, 4 waves 2x2, per-wave 32x64 via 2x4 fragments of
// v_mfma_f32_16x16x32_bf16. ONE barrier per K-iter; DMA(k+1) + A-loads(k+1) are
// issued right after the iter-k barrier, so their latency overlaps iter-k compute.
//
// Bs bank-conflict fix (R6 measured 3.1M = ~16-way on the 128 B row stride):
//   LDS slot s (16B granule) of row R stores global granule s ^ (R&7).
//   DMA side:   lane (lrow = lane>>3, s = lane&7) fetches granule s ^ lrow.
//   Read side:  granule kh*4+qa lives at slot (kh*4+qa) ^ (la&7) -> 16 la-lanes
//               spread over all 8 slot groups = 2-way aliasing = free (m136).
// A path: direct from row-major Y (A-fragment layout is row-major-compatible),
//   cvt f32->bf16 in-register; no LDS round trip.
// XCD sibling swizzle (R5): 4 n-tiles of an m-tile share id%8 -> same XCD.
// Fragment layouts (m89/m92/m97-verified):
//   A/B operand: lane l holds row (l&15), k = (l>>4)*8 + j, j=0..7
//   C/D:         col = lane&15 (N), row = (lane>>4)*4 + reg (M)
#define BM 64
#define BN 128
#define BKT 64
#define NK (H / BKT)   // 8 K-iters
__global__ __launch_bounds__(256) void gemm_sy(const float* __restrict__ Y,
                                               const __bf16* __restrict__ wb,
                                               const float* __restrict__ b2,
                                               const float* __restrict__ wo,
                                               float* __restrict__ part) {
    __shared__ __align__(16) __bf16 Bs[2][BN * BKT];   // 2 x 16 KB (DMA dest)

    const int tid  = threadIdx.x;
    const int lane = tid & 63;
    const int wave = tid >> 6;
    const int wm = wave >> 1;
    const int wn = wave & 1;
    const int la = lane & 15;
    const int qa = lane >> 4;

    // XCD-sibling swizzle decode (1-D grid of 1024)
    const int id = blockIdx.x;
    const int mt = ((id >> 5) << 3) | (id & 7);   // 0..255
    const int nt = (id >> 3) & 3;                 // 0..3
    const int m0 = mt * BM, n0 = nt * BN;

    // B-staging geometry (lane-order DMA + granule swizzle)
    const int lrow = lane >> 3;                        // 0..7
    const int lcol = (((lane & 7) ^ lrow) * 8);        // swizzled source granule

    // A direct-load row pointers: fragment mf -> row m0 + wm*32 + mf*16 + la,
    // lane k-phase starts at qa*8.
    const float* yrow0 = Y + (size_t)(m0 + wm * 32 + la) * H + qa * 8;
    const float* yrow1 = yrow0 + 16 * H;

    floatx4 acc[2][4] = {};
    float4 a[8];

    // ---- prologue: iter-0 A loads + DMA into Bs[0] ----
    a[0] = *(const float4*)(yrow0);      a[1] = *(const float4*)(yrow0 + 4);
    a[2] = *(const float4*)(yrow0 + 32); a[3] = *(const float4*)(yrow0 + 36);
    a[4] = *(const float4*)(yrow1);      a[5] = *(const float4*)(yrow1 + 4);
    a[6] = *(const float4*)(yrow1 + 32); a[7] = *(const float4*)(yrow1 + 36);
    #pragma unroll
    for (int r = 0; r < 4; ++r) {
        const int rb = r * 32 + wave * 8;
        load_lds16(wb + (size_t)(n0 + rb + lrow) * H + lcol, &Bs[0][rb * BKT]);
    }

    for (int k = 0; k < NK; ++k) {
        const int cur = k & 1;
        __syncthreads();   // drains DMA(k) + A-loads(k) [vmcnt(0)]; all waves done
                           // reading Bs[cur] from iter k-2 (same-buffer reuse safe)

        // cvt current A to fragments (frees a[] for the prefetch below)
        bf16x8 afr[2][2];
        afr[0][0] = { (__bf16)a[0].x, (__bf16)a[0].y, (__bf16)a[0].z, (__bf16)a[0].w,
                      (__bf16)a[1].x, (__bf16)a[1].y, (__bf16)a[1].z, (__bf16)a[1].w };
        afr[0][1] = { (__bf16)a[2].x, (__bf16)a[2].y, (__bf16)a[2].z, (__bf16)a[2].w,
                      (__bf16)a[3].x, (__bf16)a[3].y, (__bf16)a[3].z, (__bf16)a[3].w };
        afr[1][0] = { (__bf16)a[4].x, (__bf16)a[4].y, (__bf16)a[4].z, (__bf16)a[4].w,
                      (__bf16)a[5].x, (__bf16)a[5].y, (__bf16)a[5].z, (__bf16)a[5].w };
        afr[1][1] = { (__bf16)a[6].x, (__bf16)a[6].y, (__bf16)a[6].z, (__bf16)a[6].w,
                      (__bf16)a[7].x, (__bf16)a[7].y, (__bf16)a[7].z, (__bf16)a[7].w };

        // prefetch iter k+1 (overlaps this iter's LDS reads + MFMA)
        if (k + 1 < NK) {
            const int k1 = (k + 1) * BKT;
            #pragma unroll
            for (int r = 0; r < 4; ++r) {
                const int rb = r * 32 + wave * 8;
                load_lds16(wb + (size_t)(n0 + rb + lrow) * H + k1 + lcol,
                           &Bs[1 - cur][rb * BKT]);
            }
            a[0] = *(const float4*)(yrow0 + k1);      a[1] = *(const float4*)(yrow0 + k1 + 4);
            a[2] = *(const float4*)(yrow0 + k1 + 32); a[3] = *(const float4*)(yrow0 + k1 + 36);
            a[4] = *(const float4*)(yrow1 + k1);      a[5] = *(const float4*)(yrow1 + k1 + 4);
            a[6] = *(const float4*)(yrow1 + k1 + 32); a[7] = *(const float4*)(yrow1 + k1 + 36);
        }

        // consume Bs[cur]: swizzled fragment reads + MFMA
        #pragma unroll
        for (int kh = 0; kh < 2; ++kh) {
            bf16x8 bfr[4];
            #pragma unroll
            for (int nf = 0; nf < 4; ++nf) {
                const int row  = wn * 64 + nf * 16 + la;
                const int slot = (kh * 4 + qa) ^ (la & 7);
                bfr[nf] = *(const bf16x8*)&Bs[cur][row * BKT + slot * 8];
            }
            #pragma unroll
            for (int mf = 0; mf < 2; ++mf)
                #pragma unroll
                for (int nf = 0; nf < 4; ++nf)
                    acc[mf][nf] = __builtin_amdgcn_mfma_f32_16x16x32_bf16(afr[mf][kh], bfr[nf], acc[mf][nf], 0, 0, 0);
        }
    }

    // Epilogue: v = relu(acc + b2[n]); s = sum_n v*wo[n] over this wave's n-range;
    // xor-shuffle reduce across the 16 lanes of a row-group; deterministic store
    // into slice (nt*2 + wn) — no atomics, no zero-init needed.
    const int slice = nt * 2 + wn;
    #pragma unroll
    for (int mf = 0; mf < 2; ++mf) {
        #pragma unroll
        for (int reg = 0; reg < 4; ++reg) {
            float s = 0.f;
            #pragma unroll
            for (int nf = 0; nf < 4; ++nf) {
                const int n = n0 + wn * 64 + nf * 16 + la;
                float v = acc[mf][nf][reg] + b2[n];
                v = fmaxf(v, 0.f);
                s += v * wo[n];
            }
            s += __shfl_xor(s, 1);
            s += __shfl_xor(s, 2);
            s += __shfl_xor(s, 4);
            s += __shfl_xor(s, 8);
            if (la == 0) {
                const int m = m0 + wm * 32 + mf * 16 + qa * 4 + reg;
                part[(size_t)slice * RY + m] = s;
            }
        }
    }
}

// ---------------- softmax: reduce 8 slices + masked softmax per batch ----------------
// Masked entries exactly 0 (reference's exp(-1e7 - max) underflows to 0 in f32).
__global__ __launch_bounds__(256) void softmax_p(const float* __restrict__ part,
                                                 const int* __restrict__ mask,
                                                 float* __restrict__ p) {
    const int b = blockIdx.x;
    const int tid = threadIdx.x;
    __shared__ float red[8];

    float vals[4];
    int   ms[4];
    float mx = -INFINITY;
    #pragma unroll
    for (int c = 0; c < 4; ++c) {
        const int j = c * 256 + tid;
        float v = 0.f;
        #pragma unroll
        for (int t = 0; t < 8; ++t) v += part[t * RY + b * LY + j];
        vals[c] = v;
        ms[c]   = mask[b * LY + j];
        if (!ms[c]) mx = fmaxf(mx, v);
    }
    #pragma unroll
    for (int off = 1; off < 64; off <<= 1) mx = fmaxf(mx, __shfl_xor(mx, off));
    if ((tid & 63) == 0) red[tid >> 6] = mx;
    __syncthreads();
    mx = fmaxf(fmaxf(red[0], red[1]), fmaxf(red[2], red[3]));

    float e[4];
    float sum = 0.f;
    #pragma unroll
    for (int c = 0; c < 4; ++c) {
        e[c] = ms[c] ? 0.f : __expf(vals[c] - mx);
        sum += e[c];
    }
    #pragma unroll
    for (int off = 1; off < 64; off <<= 1) sum += __shfl_xor(sum, off);
    if ((tid & 63) == 0) red[4 + (tid >> 6)] = sum;
    __syncthreads();
    sum = red[4] + red[5] + red[6] + red[7];
    const float inv = 1.0f / sum;

    #pragma unroll
    for (int c = 0; c < 4; ++c)
        p[b * LY + c * 256 + tid] = e[c] * inv;
}

// ---------------- bcast: out[b,i,j] = p[b,j] ----------------
// Each block: 8 output rows; thread: 1 float4 load (L2-hot), 8 coalesced float4 stores.
__global__ __launch_bounds__(256) void bcast(const float* __restrict__ p,
                                             float4* __restrict__ out) {
    const int tid = threadIdx.x;
    const long base_row = (long)blockIdx.x * 8;        // [0, BS*LX)
    const int b = (int)(base_row >> 10);               // 8 | 1024: rows share b
    const float4 v = *(const float4*)(p + b * LY + tid * 4);
    float4* o = out + base_row * (LY / 4) + tid;
    #pragma unroll
    for (int r = 0; r < 8; ++r) o[r * (LY / 4)] = v;
}

extern "C" void kernel_launch(void* const* d_in, const int* in_sizes, int n_in,
                              void* d_out, int out_size, void* d_ws, size_t ws_size,
                              hipStream_t stream) {
    // setup_inputs order: x, y, y_mask, W1, b1, W2, b2, w_o, b_o
    const float* y  = (const float*)d_in[1];
    const int*   ym = (const int*)  d_in[2];
    const float* W2 = (const float*)d_in[5];
    const float* b2 = (const float*)d_in[6];
    const float* wo = (const float*)d_in[7];
    // x, W1, b1, b_o are mathematically irrelevant to alpha (softmax shift-invariance).

    // Workspace layout (16B-aligned):
    char* ws = (char*)d_ws;
    __bf16* wb   = (__bf16*)ws;                          // MD*H bf16 = 0.5 MB
    float*  part = (float*)(ws + (size_t)MD * H * 2);    // 8*RY f32
    float*  p    = part + 8 * RY;                        // RY f32

    prep_w2<<<(MD * H) / (256 * 8), 256, 0, stream>>>(W2, wb);
    gemm_sy<<<(MD / BN) * (RY / BM), 256, 0, stream>>>(y, wb, b2, wo, part);  // 1024 blocks, swizzled
    softmax_p<<<BS, 256, 0, stream>>>(part, ym, p);
    bcast<<<(BS * LX) / 8, 256, 0, stream>>>(p, (float4*)d_out);
}

// Round 8
// 157.784 us; speedup vs baseline: 1.0467x; 1.0467x over previous
//
#include <hip/hip_runtime.h>
#include <hip/hip_bf16.h>

// Problem constants
#define BS 16
#define LX 1024
#define LY 1024
#define H 512
#define MD 512
#define RY (BS * LY)   // 16384 rows of y

typedef __attribute__((ext_vector_type(8))) __bf16 bf16x8;
typedef __attribute__((ext_vector_type(4))) float floatx4;

// Async global->LDS, 16B per lane. HW dest = wave-uniform base + lane*16
// (guide §5 caveat m104/m108) — LDS layout must be contiguous in lane order.
__device__ __forceinline__ void load_lds16(const __bf16* g, __bf16* l) {
    __builtin_amdgcn_global_load_lds(
        (const __attribute__((address_space(1))) void*)g,
        (__attribute__((address_space(3))) void*)l,
        16, 0, 0);
}

// ---------------- prep_w2: f32 -> bf16 for W2 only (1 MB read) ----------------
__global__ __launch_bounds__(256) void prep_w2(const float* __restrict__ W2,
                                               __bf16* __restrict__ wb) {
    const int i = blockIdx.x * 256 + threadIdx.x;   // 0..32767, x8 floats
    const float4 a = *(const float4*)(W2 + (size_t)i * 8);
    const float4 b = *(const float4*)(W2 + (size_t)i * 8 + 4);
    bf16x8 v = { (__bf16)a.x, (__bf16)a.y, (__bf16)a.z, (__bf16)a.w,
                 (__bf16)b.x, (__bf16)b.y, (__bf16)b.z, (__bf16)b.w };
    *(bf16x8*)(wb + (size_t)i * 8) = v;
}

// ---------------- gemm: part[slice, m] = sum_n wo[n]*relu(Y@W2^T + b2) ----------------
// R8: BARRIER-FREE K-loop. The block's whole B n-slice (64 rows x 512 k = 64 KB bf16)
// is staged into LDS ONCE (16 row-DMAs/wave, XOR-swizzled slots — R7's measured
// zero-conflict pattern), then one __syncthreads, then 8 K-iters with NO barriers:
//   A: direct from row-major Y in fragment layout (2 float4/lane/fragment, cvt in reg)
//   B: ds_read_b128 from resident LDS
// With no vmcnt(0)-draining barrier in the loop, A-loads of iter k+1 overlap iter-k
// MFMA (R7's failure mode was the per-iter barrier drain; R6/R7 measured ~94% stall).
// Tile: BM=128 x BN=64, 4 waves each m-quarter (32 rows) x all 64 n.
// LDS 64 KB -> 2 blocks/CU (__launch_bounds__(256,2)) = 8 waves/CU.
// Swizzle: slot s of row R holds global granule s^(R&7); read slot = g ^ (la&7).
// XCD sibling swizzle: 8 n-tiles of an m-tile share id&7 -> same XCD (Y L2-hot):
//   mt = ((id>>6)<<3)|(id&7);  nt = (id>>3)&7.
// Fragment layouts (m89/m92/m97-verified):
//   A/B operand: lane l holds row (l&15), k = (l>>4)*8 + j, j=0..7
//   C/D:         col = lane&15 (N), row = (lane>>4)*4 + reg (M)
#define BM 128
#define BN 64
#define BKT 64
#define NK (H / BKT)   // 8 K-iters
__global__ __launch_bounds__(256, 2) void gemm_sy(const float* __restrict__ Y,
                                                  const __bf16* __restrict__ wb,
                                                  const float* __restrict__ b2,
                                                  const float* __restrict__ wo,
                                                  float* __restrict__ part) {
    __shared__ __align__(16) __bf16 Bs[BN * H];   // 64 KB, resident all kernel

    const int tid  = threadIdx.x;
    const int lane = tid & 63;
    const int wave = tid >> 6;
    const int la = lane & 15;
    const int qa = lane >> 4;

    // XCD-sibling swizzle decode (1-D grid of 1024)
    const int id = blockIdx.x;
    const int mt = ((id >> 6) << 3) | (id & 7);   // 0..127
    const int nt = (id >> 3) & 7;                 // 0..7
    const int m0 = mt * BM, n0 = nt * BN;

    // ---- stage whole B n-slice once: wave stages rows wave*16..+15 (1 KB row = 1 DMA).
    // Lane l fetches granule l^(row&7) -> lands at LDS slot l => stored[s] = granule s^(row&7).
    #pragma unroll
    for (int r = 0; r < 16; ++r) {
        const int row = wave * 16 + r;
        const int g   = lane ^ (row & 7);
        load_lds16(wb + (size_t)(n0 + row) * H + g * 8, &Bs[row * H]);
    }
    __syncthreads();   // the ONLY barrier: drains staging DMA

    // A direct-load row pointers: wave covers m-quarter wave*32; fragment mf: +mf*16.
    const float* yrow0 = Y + (size_t)(m0 + wave * 32 + la) * H + qa * 8;
    const float* yrow1 = yrow0 + 16 * H;

    floatx4 acc[2][4] = {};
    float4 a[8];

    // prologue A-loads (iter 0)
    a[0] = *(const float4*)(yrow0);      a[1] = *(const float4*)(yrow0 + 4);
    a[2] = *(const float4*)(yrow0 + 32); a[3] = *(const float4*)(yrow0 + 36);
    a[4] = *(const float4*)(yrow1);      a[5] = *(const float4*)(yrow1 + 4);
    a[6] = *(const float4*)(yrow1 + 32); a[7] = *(const float4*)(yrow1 + 36);

    for (int k = 0; k < NK; ++k) {
        // cvt current A to fragments (frees a[] for next-iter prefetch)
        bf16x8 afr[2][2];
        afr[0][0] = { (__bf16)a[0].x, (__bf16)a[0].y, (__bf16)a[0].z, (__bf16)a[0].w,
                      (__bf16)a[1].x, (__bf16)a[1].y, (__bf16)a[1].z, (__bf16)a[1].w };
        afr[0][1] = { (__bf16)a[2].x, (__bf16)a[2].y, (__bf16)a[2].z, (__bf16)a[2].w,
                      (__bf16)a[3].x, (__bf16)a[3].y, (__bf16)a[3].z, (__bf16)a[3].w };
        afr[1][0] = { (__bf16)a[4].x, (__bf16)a[4].y, (__bf16)a[4].z, (__bf16)a[4].w,
                      (__bf16)a[5].x, (__bf16)a[5].y, (__bf16)a[5].z, (__bf16)a[5].w };
        afr[1][1] = { (__bf16)a[6].x, (__bf16)a[6].y, (__bf16)a[6].z, (__bf16)a[6].w,
                      (__bf16)a[7].x, (__bf16)a[7].y, (__bf16)a[7].z, (__bf16)a[7].w };

        // prefetch next iter's A (no barrier anywhere -> overlaps MFMA below)
        if (k + 1 < NK) {
            const int k1 = (k + 1) * BKT;
            a[0] = *(const float4*)(yrow0 + k1);      a[1] = *(const float4*)(yrow0 + k1 + 4);
            a[2] = *(const float4*)(yrow0 + k1 + 32); a[3] = *(const float4*)(yrow0 + k1 + 36);
            a[4] = *(const float4*)(yrow1 + k1);      a[5] = *(const float4*)(yrow1 + k1 + 4);
            a[6] = *(const float4*)(yrow1 + k1 + 32); a[7] = *(const float4*)(yrow1 + k1 + 36);
        }

        // B fragments from resident LDS (swizzled slots) + MFMA
        const int gbase = k * (BKT / 8);   // granule base = k0/8
        #pragma unroll
        for (int kh = 0; kh < 2; ++kh) {
            bf16x8 bfr[4];
            #pragma unroll
            for (int nf = 0; nf < 4; ++nf) {
                const int row  = nf * 16 + la;
                const int slot = (gbase + kh * 4 + qa) ^ (la & 7);
                bfr[nf] = *(const bf16x8*)&Bs[row * H + slot * 8];
            }
            #pragma unroll
            for (int mf = 0; mf < 2; ++mf)
                #pragma unroll
                for (int nf = 0; nf < 4; ++nf)
                    acc[mf][nf] = __builtin_amdgcn_mfma_f32_16x16x32_bf16(afr[mf][kh], bfr[nf], acc[mf][nf], 0, 0, 0);
        }
    }

    // Epilogue: v = relu(acc + b2[n]); s = sum_n v*wo[n] over this block's n-slice;
    // xor-shuffle reduce across the 16 la-lanes; deterministic store into slice nt.
    #pragma unroll
    for (int mf = 0; mf < 2; ++mf) {
        #pragma unroll
        for (int reg = 0; reg < 4; ++reg) {
            float s = 0.f;
            #pragma unroll
            for (int nf = 0; nf < 4; ++nf) {
                const int n = n0 + nf * 16 + la;
                float v = acc[mf][nf][reg] + b2[n];
                v = fmaxf(v, 0.f);
                s += v * wo[n];
            }
            s += __shfl_xor(s, 1);
            s += __shfl_xor(s, 2);
            s += __shfl_xor(s, 4);
            s += __shfl_xor(s, 8);
            if (la == 0) {
                const int m = m0 + wave * 32 + mf * 16 + qa * 4 + reg;
                part[(size_t)nt * RY + m] = s;
            }
        }
    }
}

// ---------------- softmax: reduce 8 slices + masked softmax per batch ----------------
// Masked entries exactly 0 (reference's exp(-1e7 - max) underflows to 0 in f32).
__global__ __launch_bounds__(256) void softmax_p(const float* __restrict__ part,
                                                 const int* __restrict__ mask,
                                                 float* __restrict__ p) {
    const int b = blockIdx.x;
    const int tid = threadIdx.x;
    __shared__ float red[8];

    float vals[4];
    int   ms[4];
    float mx = -INFINITY;
    #pragma unroll
    for (int c = 0; c < 4; ++c) {
        const int j = c * 256 + tid;
        float v = 0.f;
        #pragma unroll
        for (int t = 0; t < 8; ++t) v += part[t * RY + b * LY + j];
        vals[c] = v;
        ms[c]   = mask[b * LY + j];
        if (!ms[c]) mx = fmaxf(mx, v);
    }
    #pragma unroll
    for (int off = 1; off < 64; off <<= 1) mx = fmaxf(mx, __shfl_xor(mx, off));
    if ((tid & 63) == 0) red[tid >> 6] = mx;
    __syncthreads();
    mx = fmaxf(fmaxf(red[0], red[1]), fmaxf(red[2], red[3]));

    float e[4];
    float sum = 0.f;
    #pragma unroll
    for (int c = 0; c < 4; ++c) {
        e[c] = ms[c] ? 0.f : __expf(vals[c] - mx);
        sum += e[c];
    }
    #pragma unroll
    for (int off = 1; off < 64; off <<= 1) sum += __shfl_xor(sum, off);
    if ((tid & 63) == 0) red[4 + (tid >> 6)] = sum;
    __syncthreads();
    sum = red[4] + red[5] + red[6] + red[7];
    const float inv = 1.0f / sum;

    #pragma unroll
    for (int c = 0; c < 4; ++c)
        p[b * LY + c * 256 + tid] = e[c] * inv;
}

// ---------------- bcast: out[b,i,j] = p[b,j] ----------------
// Each block: 8 output rows; thread: 1 float4 load (L2-hot), 8 coalesced float4 stores.
__global__ __launch_bounds__(256) void bcast(const float* __restrict__ p,
                                             float4* __restrict__ out) {
    const int tid = threadIdx.x;
    const long base_row = (long)blockIdx.x * 8;        // [0, BS*LX)
    const int b = (int)(base_row >> 10);               // 8 | 1024: rows share b
    const float4 v = *(const float4*)(p + b * LY + tid * 4);
    float4* o = out + base_row * (LY / 4) + tid;
    #pragma unroll
    for (int r = 0; r < 8; ++r) o[r * (LY / 4)] = v;
}

extern "C" void kernel_launch(void* const* d_in, const int* in_sizes, int n_in,
                              void* d_out, int out_size, void* d_ws, size_t ws_size,
                              hipStream_t stream) {
    // setup_inputs order: x, y, y_mask, W1, b1, W2, b2, w_o, b_o
    const float* y  = (const float*)d_in[1];
    const int*   ym = (const int*)  d_in[2];
    const float* W2 = (const float*)d_in[5];
    const float* b2 = (const float*)d_in[6];
    const float* wo = (const float*)d_in[7];
    // x, W1, b1, b_o are mathematically irrelevant to alpha (softmax shift-invariance).

    // Workspace layout (16B-aligned):
    char* ws = (char*)d_ws;
    __bf16* wb   = (__bf16*)ws;                          // MD*H bf16 = 0.5 MB
    float*  part = (float*)(ws + (size_t)MD * H * 2);    // 8*RY f32
    float*  p    = part + 8 * RY;                        // RY f32

    prep_w2<<<(MD * H) / (256 * 8), 256, 0, stream>>>(W2, wb);
    gemm_sy<<<(MD / BN) * (RY / BM), 256, 0, stream>>>(y, wb, b2, wo, part);  // 1024 blocks
    softmax_p<<<BS, 256, 0, stream>>>(part, ym, p);
    bcast<<<(BS * LX) / 8, 256, 0, stream>>>(p, (float4*)d_out);
}

// Round 9
// 145.989 us; speedup vs baseline: 1.1312x; 1.0808x over previous
//
#include <hip/hip_runtime.h>
#include <hip/hip_bf16.h>

// Problem constants
#define BS 16
#define LX 1024
#define LY 1024
#define H 512
#define MD 512
#define RY (BS * LY)   // 16384 rows of y

typedef __attribute__((ext_vector_type(8))) __bf16 bf16x8;
typedef __attribute__((ext_vector_type(4))) float floatx4;

// Async global->LDS, 16B per lane. HW dest = wave-uniform base + lane*16
// (guide §5 caveat m104/m108) — LDS layout must be contiguous in lane order.
__device__ __forceinline__ void load_lds16(const __bf16* g, __bf16* l) {
    __builtin_amdgcn_global_load_lds(
        (const __attribute__((address_space(1))) void*)g,
        (__attribute__((address_space(3))) void*)l,
        16, 0, 0);
}

// ---------------- prep_w2: f32 -> bf16 for W2 only (1 MB read) ----------------
__global__ __launch_bounds__(256) void prep_w2(const float* __restrict__ W2,
                                               __bf16* __restrict__ wb) {
    const int i = blockIdx.x * 256 + threadIdx.x;   // 0..32767, x8 floats
    const float4 a = *(const float4*)(W2 + (size_t)i * 8);
    const float4 b = *(const float4*)(W2 + (size_t)i * 8 + 4);
    bf16x8 v = { (__bf16)a.x, (__bf16)a.y, (__bf16)a.z, (__bf16)a.w,
                 (__bf16)b.x, (__bf16)b.y, (__bf16)b.z, (__bf16)b.w };
    *(bf16x8*)(wb + (size_t)i * 8) = v;
}

// ---------------- gemm: part[slice, m] = sum_n wo[n]*relu(Y@W2^T + b2) ----------------
// R9 = R5 (best measured: coalesced A via padded LDS, per-iter B-DMA, 2 barriers,
// XCD sibling swizzle) + Bs XOR-granule swizzle (R7/R8-proven zero-conflict, removes
// the 3.1M conflict cycles R6 measured on the unpadded 128 B Bs row stride).
// Tile 64(M) x 128(N), BK=64, 4 waves 2x2, per-wave 32x64 via 2x4 fragments of
// v_mfma_f32_16x16x32_bf16.
// Bs swizzle: LDS slot s (16B granule) of row R stores global granule s^(R&7).
//   DMA:  lane (lrow=lane>>3, s=lane&7) fetches granule s^lrow (same cache lines).
//   Read: granule kh*4+qa of row R is at slot (kh*4+qa)^(R&7), R&7 = la&7
//         -> 16 la-lanes spread across all 8 slot groups (even = conflict-free).
// A path: coalesced f32 float4 loads -> cvt bf16 -> padded LDS (ASTR=72: banks
//   spread 4*(la+qa) mod 32 = even 8-lane groups, minimum cycles).
// XCD sibling swizzle (R5): 4 n-tiles of an m-tile share id%8 -> same XCD:
//   mt = ((id>>5)<<3)|(id&7);  nt = (id>>3)&3.
// Fragment layouts (m89/m92/m97-verified):
//   A/B operand: lane l holds row (l&15), k = (l>>4)*8 + j, j=0..7
//   C/D:         col = lane&15 (N), row = (lane>>4)*4 + reg (M)
#define BM 64
#define BN 128
#define BKT 64
#define ASTR 72   // bf16 elems per A-row in LDS (144 B)
__global__ __launch_bounds__(256) void gemm_sy(const float* __restrict__ Y,
                                               const __bf16* __restrict__ wb,
                                               const float* __restrict__ b2,
                                               const float* __restrict__ wo,
                                               float* __restrict__ part) {
    __shared__ __align__(16) __bf16 As[BM * ASTR];   // 9216 B, padded
    __shared__ __align__(16) __bf16 Bs[BN * BKT];    // 16384 B, swizzled (DMA dest)

    const int tid  = threadIdx.x;
    const int lane = tid & 63;
    const int wave = tid >> 6;
    const int wm = wave >> 1;
    const int wn = wave & 1;
    const int la = lane & 15;
    const int qa = lane >> 4;

    // XCD-sibling swizzle decode (1-D grid of 1024)
    const int id = blockIdx.x;
    const int mt = ((id >> 5) << 3) | (id & 7);   // 0..255
    const int nt = (id >> 3) & 3;                 // 0..3
    const int m0 = mt * BM, n0 = nt * BN;

    // B-staging geometry (lane-order DMA + XOR granule swizzle)
    const int lrow = lane >> 3;                        // 0..7
    const int lcol = ((lane & 7) ^ lrow) * 8;          // swizzled source granule

    // A-staging geometry: thread t -> row t>>2, 16 consecutive f32 at col (t&3)*16
    const int ar = tid >> 2;
    const int ac = (tid & 3) * 16;
    const float* ybase = Y + (size_t)(m0 + ar) * H + ac;

    floatx4 acc[2][4] = {};

    for (int k0 = 0; k0 < H; k0 += BKT) {
        __syncthreads();
        // B: async DMA first so it overlaps the A VGPR path. 4 rounds x (4 waves x 8 rows).
        #pragma unroll
        for (int r = 0; r < 4; ++r) {
            const int rb = r * 32 + wave * 8;   // rb+lrow ≡ lrow (mod 8)
            load_lds16(wb + (size_t)(n0 + rb + lrow) * H + k0 + lcol, &Bs[rb * BKT]);
        }
        // A: 16 f32 per thread -> 16 bf16 -> two 16B LDS writes (padded stride).
        const float4 a0 = *(const float4*)(ybase + k0);
        const float4 a1 = *(const float4*)(ybase + k0 + 4);
        const float4 a2 = *(const float4*)(ybase + k0 + 8);
        const float4 a3 = *(const float4*)(ybase + k0 + 12);
        bf16x8 p0 = { (__bf16)a0.x, (__bf16)a0.y, (__bf16)a0.z, (__bf16)a0.w,
                      (__bf16)a1.x, (__bf16)a1.y, (__bf16)a1.z, (__bf16)a1.w };
        bf16x8 p1 = { (__bf16)a2.x, (__bf16)a2.y, (__bf16)a2.z, (__bf16)a2.w,
                      (__bf16)a3.x, (__bf16)a3.y, (__bf16)a3.z, (__bf16)a3.w };
        *(bf16x8*)&As[ar * ASTR + ac]     = p0;
        *(bf16x8*)&As[ar * ASTR + ac + 8] = p1;
        __syncthreads();   // drains lds-DMA (vmcnt) + ds_write (lgkmcnt)

        #pragma unroll
        for (int kh = 0; kh < 2; ++kh) {
            bf16x8 afr[2], bfr[4];
            #pragma unroll
            for (int mf = 0; mf < 2; ++mf)
                afr[mf] = *(const bf16x8*)&As[(wm * 32 + mf * 16 + la) * ASTR + kh * 32 + qa * 8];
            #pragma unroll
            for (int nf = 0; nf < 4; ++nf) {
                const int row  = wn * 64 + nf * 16 + la;
                const int slot = (kh * 4 + qa) ^ (la & 7);
                bfr[nf] = *(const bf16x8*)&Bs[row * BKT + slot * 8];
            }
            #pragma unroll
            for (int mf = 0; mf < 2; ++mf)
                #pragma unroll
                for (int nf = 0; nf < 4; ++nf)
                    acc[mf][nf] = __builtin_amdgcn_mfma_f32_16x16x32_bf16(afr[mf], bfr[nf], acc[mf][nf], 0, 0, 0);
        }
    }

    // Epilogue: v = relu(acc + b2[n]); s = sum_n v*wo[n] over this wave's n-range;
    // xor-shuffle reduce across the 16 lanes of a row-group; deterministic store
    // into slice (nt*2 + wn) — no atomics, no zero-init needed.
    const int slice = nt * 2 + wn;
    #pragma unroll
    for (int mf = 0; mf < 2; ++mf) {
        #pragma unroll
        for (int reg = 0; reg < 4; ++reg) {
            float s = 0.f;
            #pragma unroll
            for (int nf = 0; nf < 4; ++nf) {
                const int n = n0 + wn * 64 + nf * 16 + la;
                float v = acc[mf][nf][reg] + b2[n];
                v = fmaxf(v, 0.f);
                s += v * wo[n];
            }
            s += __shfl_xor(s, 1);
            s += __shfl_xor(s, 2);
            s += __shfl_xor(s, 4);
            s += __shfl_xor(s, 8);
            if (la == 0) {
                const int m = m0 + wm * 32 + mf * 16 + qa * 4 + reg;
                part[(size_t)slice * RY + m] = s;
            }
        }
    }
}

// ---------------- softmax: reduce 8 slices + masked softmax per batch ----------------
// Masked entries exactly 0 (reference's exp(-1e7 - max) underflows to 0 in f32).
__global__ __launch_bounds__(256) void softmax_p(const float* __restrict__ part,
                                                 const int* __restrict__ mask,
                                                 float* __restrict__ p) {
    const int b = blockIdx.x;
    const int tid = threadIdx.x;
    __shared__ float red[8];

    float vals[4];
    int   ms[4];
    float mx = -INFINITY;
    #pragma unroll
    for (int c = 0; c < 4; ++c) {
        const int j = c * 256 + tid;
        float v = 0.f;
        #pragma unroll
        for (int t = 0; t < 8; ++t) v += part[t * RY + b * LY + j];
        vals[c] = v;
        ms[c]   = mask[b * LY + j];
        if (!ms[c]) mx = fmaxf(mx, v);
    }
    #pragma unroll
    for (int off = 1; off < 64; off <<= 1) mx = fmaxf(mx, __shfl_xor(mx, off));
    if ((tid & 63) == 0) red[tid >> 6] = mx;
    __syncthreads();
    mx = fmaxf(fmaxf(red[0], red[1]), fmaxf(red[2], red[3]));

    float e[4];
    float sum = 0.f;
    #pragma unroll
    for (int c = 0; c < 4; ++c) {
        e[c] = ms[c] ? 0.f : __expf(vals[c] - mx);
        sum += e[c];
    }
    #pragma unroll
    for (int off = 1; off < 64; off <<= 1) sum += __shfl_xor(sum, off);
    if ((tid & 63) == 0) red[4 + (tid >> 6)] = sum;
    __syncthreads();
    sum = red[4] + red[5] + red[6] + red[7];
    const float inv = 1.0f / sum;

    #pragma unroll
    for (int c = 0; c < 4; ++c)
        p[b * LY + c * 256 + tid] = e[c] * inv;
}

// ---------------- bcast: out[b,i,j] = p[b,j] ----------------
// Each block: 8 output rows; thread: 1 float4 load (L2-hot), 8 coalesced float4 stores.
__global__ __launch_bounds__(256) void bcast(const float* __restrict__ p,
                                             float4* __restrict__ out) {
    const int tid = threadIdx.x;
    const long base_row = (long)blockIdx.x * 8;        // [0, BS*LX)
    const int b = (int)(base_row >> 10);               // 8 | 1024: rows share b
    const float4 v = *(const float4*)(p + b * LY + tid * 4);
    float4* o = out + base_row * (LY / 4) + tid;
    #pragma unroll
    for (int r = 0; r < 8; ++r) o[r * (LY / 4)] = v;
}

extern "C" void kernel_launch(void* const* d_in, const int* in_sizes, int n_in,
                              void* d_out, int out_size, void* d_ws, size_t ws_size,
                              hipStream_t stream) {
    // setup_inputs order: x, y, y_mask, W1, b1, W2, b2, w_o, b_o
    const float* y  = (const float*)d_in[1];
    const int*   ym = (const int*)  d_in[2];
    const float* W2 = (const float*)d_in[5];
    const float* b2 = (const float*)d_in[6];
    const float* wo = (const float*)d_in[7];
    // x, W1, b1, b_o are mathematically irrelevant to alpha (softmax shift-invariance).

    // Workspace layout (16B-aligned):
    char* ws = (char*)d_ws;
    __bf16* wb   = (__bf16*)ws;                          // MD*H bf16 = 0.5 MB
    float*  part = (float*)(ws + (size_t)MD * H * 2);    // 8*RY f32
    float*  p    = part + 8 * RY;                        // RY f32

    prep_w2<<<(MD * H) / (256 * 8), 256, 0, stream>>>(W2, wb);
    gemm_sy<<<(MD / BN) * (RY / BM), 256, 0, stream>>>(y, wb, b2, wo, part);  // 1024 blocks, swizzled
    softmax_p<<<BS, 256, 0, stream>>>(part, ym, p);
    bcast<<<(BS * LX) / 8, 256, 0, stream>>>(p, (float4*)d_out);
}